// Round 5
// baseline (1969.854 us; speedup 1.0000x reference)
//
#include <hip/hip_runtime.h>
#include <hip/hip_bf16.h>

// Problem constants
#define T_TOK 6272      // B*D*H*W tokens (2*16*14*14)
#define CDIM  768
#define NTOK  392       // tokens per window (8*7*7)
#define NWIN  16        // total windows (B=2 * 8)
#define NHEADS 24
#define HDIM  32
#define QSCALE 0.17677669529663687f  // 32^-0.5

// attention MFMA geometry
#define NKT 26          // key tiles of 16 -> 416 (keys 392..415 masked)
#define NQT 25          // query tiles of 16 -> 400 (rows >=392 clamped, not written)
#define KS_ST 40        // K LDS row stride (elems): 80B -> 2-way (free) b128 col reads
#define VS_ST 456       // V^T LDS row stride (elems): 912B -> 2-way (free)
#define PS_ST 424       // P LDS row stride (elems): 848B, 16B-aligned rows

typedef unsigned short ushort_t;
typedef __attribute__((ext_vector_type(8))) short bf16x8;
typedef __attribute__((ext_vector_type(4))) short bf16x4;
typedef __attribute__((ext_vector_type(4))) float f32x4;

__device__ __forceinline__ float bf2f(ushort_t h) {
    union { unsigned int u; float f; } v; v.u = ((unsigned int)h) << 16; return v.f;
}
__device__ __forceinline__ ushort_t f2bf(float f) {
    return __bfloat16_as_ushort(__float2bfloat16(f));
}
__device__ __forceinline__ float gelu_f(float x) {
    return 0.5f * x * (1.0f + erff(x * 0.70710678118654752f));
}

// async global->LDS, 16B per lane. LDS dest is wave-uniform base; HW writes
// lane i at base + i*16B. Global src is per-lane.
__device__ __forceinline__ void gload16(const ushort_t* g, ushort_t* l) {
    __builtin_amdgcn_global_load_lds(
        (const __attribute__((address_space(1))) void*)g,
        (__attribute__((address_space(3))) void*)l,
        16, 0, 0);
}

// ---------------------------------------------------------------------------
// (B,C,D,H,W) f32 -> X[t][c] f32
__global__ __launch_bounds__(256) void k_transpose_in(const float* __restrict__ x,
                                                      float* __restrict__ X) {
    __shared__ float tile[32][33];
    int b  = blockIdx.z;
    int s0 = blockIdx.x * 32, c0 = blockIdx.y * 32;
    int tx = threadIdx.x, ty = threadIdx.y;
#pragma unroll
    for (int r = 0; r < 4; ++r)
        tile[ty + r * 8][tx] = x[((size_t)b * 768 + c0 + ty + r * 8) * 3136 + s0 + tx];
    __syncthreads();
#pragma unroll
    for (int r = 0; r < 4; ++r)
        X[((size_t)b * 3136 + s0 + ty + r * 8) * 768 + c0 + tx] = tile[tx][ty + r * 8];
}

// ---------------------------------------------------------------------------
// f32 -> bf16 elementwise, 4 elems/thread (n must be multiple of 4)
__global__ __launch_bounds__(256) void k_f2b(const float* __restrict__ s,
                                             ushort_t* __restrict__ d, int n4) {
    int i = blockIdx.x * 256 + threadIdx.x;
    if (i >= n4) return;
    float4 v = ((const float4*)s)[i];
    bf16x4 r;
    r[0] = (short)f2bf(v.x); r[1] = (short)f2bf(v.y);
    r[2] = (short)f2bf(v.z); r[3] = (short)f2bf(v.w);
    *(bf16x4*)&d[(size_t)i * 4] = r;
}

// ---------------------------------------------------------------------------
// rpb [2535][24] f32 -> rpbT [24][2535] f32
__global__ __launch_bounds__(256) void k_rpbT(const float* __restrict__ rpb,
                                              float* __restrict__ rpbT) {
    int idx = blockIdx.x * 256 + threadIdx.x;
    if (idx >= 24 * 2535) return;
    int h = idx / 2535, r = idx - h * 2535;
    rpbT[idx] = rpb[(size_t)r * 24 + h];
}

// Bias[h][i][j] bf16 = rpbT[h][rpi[i][j]]; j in [0,416), cols >=392 are 0.
// One block per (h,i) row.
__global__ __launch_bounds__(256) void k_bias(const float* __restrict__ rpbT,
                                              const int* __restrict__ rpi,
                                              ushort_t* __restrict__ Bias) {
    int row = blockIdx.x;          // row = h*392 + i
    int h = row / 392, i = row - h * 392;
    const float* rp = rpbT + (size_t)h * 2535;
    const int* ri = rpi + (size_t)i * NTOK;
    ushort_t* out = Bias + (size_t)row * 416;
    for (int j = threadIdx.x; j < 416; j += 256) {
        float v = (j < NTOK) ? rp[ri[j]] : 0.f;
        out[j] = f2bf(v);
    }
}

// ---------------------------------------------------------------------------
// LayerNorm, bf16 output. mode 0: identity rows. mode 1: window-gather.
// mode 2: window-gather with roll(-4,-3,-3) folded in.
__global__ __launch_bounds__(256) void k_ln_bf(const float* __restrict__ X,
                                               ushort_t* __restrict__ Y,
                                               const float* __restrict__ g,
                                               const float* __restrict__ bta,
                                               int mode) {
    int row = blockIdx.x;
    int src = row;
    if (mode != 0) {
        int wi = row / NTOK, n = row % NTOK;
        int b = wi >> 3, rem = wi & 7;
        int wd = rem >> 2, wh = (rem >> 1) & 1, ww = rem & 1;
        int dn = n / 49, r2 = n % 49, hn = r2 / 7, wn = r2 % 7;
        int d = wd * 8 + dn, h = wh * 7 + hn, w = ww * 7 + wn;
        if (mode == 2) { d = (d + 4) & 15; h = (h + 3) % 14; w = (w + 3) % 14; }
        src = (b * 16 + d) * 196 + h * 14 + w;
    }
    const float* xr = X + (size_t)src * CDIM;
    int tid = threadIdx.x;
    float v0 = xr[tid], v1 = xr[tid + 256], v2 = xr[tid + 512];
    float s = v0 + v1 + v2;
    float q = v0 * v0 + v1 * v1 + v2 * v2;
    __shared__ float red[8];
#pragma unroll
    for (int off = 32; off > 0; off >>= 1) {
        s += __shfl_down(s, off);
        q += __shfl_down(q, off);
    }
    int lane = tid & 63, wv = tid >> 6;
    if (lane == 0) { red[wv] = s; red[4 + wv] = q; }
    __syncthreads();
    float ts = red[0] + red[1] + red[2] + red[3];
    float tq = red[4] + red[5] + red[6] + red[7];
    float mu  = ts * (1.0f / 768.0f);
    float var = tq * (1.0f / 768.0f) - mu * mu;
    float rstd = rsqrtf(var + 1e-5f);
    ushort_t* yr = Y + (size_t)row * CDIM;
    yr[tid]       = f2bf((v0 - mu) * rstd * g[tid]       + bta[tid]);
    yr[tid + 256] = f2bf((v1 - mu) * rstd * g[tid + 256] + bta[tid + 256]);
    yr[tid + 512] = f2bf((v2 - mu) * rstd * g[tid + 512] + bta[tid + 512]);
}

// LayerNorm, f32 output, identity rows (head path only).
__global__ __launch_bounds__(256) void k_ln_f32(const float* __restrict__ X,
                                                float* __restrict__ Y,
                                                const float* __restrict__ g,
                                                const float* __restrict__ bta) {
    int row = blockIdx.x, tid = threadIdx.x;
    const float* xr = X + (size_t)row * CDIM;
    float v0 = xr[tid], v1 = xr[tid + 256], v2 = xr[tid + 512];
    float s = v0 + v1 + v2;
    float q = v0 * v0 + v1 * v1 + v2 * v2;
    __shared__ float red[8];
#pragma unroll
    for (int off = 32; off > 0; off >>= 1) {
        s += __shfl_down(s, off);
        q += __shfl_down(q, off);
    }
    int lane = tid & 63, wv = tid >> 6;
    if (lane == 0) { red[wv] = s; red[4 + wv] = q; }
    __syncthreads();
    float ts = red[0] + red[1] + red[2] + red[3];
    float tq = red[4] + red[5] + red[6] + red[7];
    float mu  = ts * (1.0f / 768.0f);
    float var = tq * (1.0f / 768.0f) - mu * mu;
    float rstd = rsqrtf(var + 1e-5f);
    float* yr = Y + (size_t)row * CDIM;
    yr[tid]       = (v0 - mu) * rstd * g[tid]       + bta[tid];
    yr[tid + 256] = (v1 - mu) * rstd * g[tid + 256] + bta[tid + 256];
    yr[tid + 512] = (v2 - mu) * rstd * g[tid + 512] + bta[tid + 512];
}

// ---------------------------------------------------------------------------
// MFMA GEMM: C[M,N] = act(A[M,K] @ W[N,K]^T + bias)
// A, W bf16 row-major [rows][K]; 128x128 tile, BK=32, 4 waves (2x2 quads),
// each wave a 4x4 grid of 16x16x32 MFMAs.
// Staging: global_load_lds width=16, DOUBLE-BUFFERED 2-phase: issue next
// K-step's loads into buf^1 BEFORE computing buf; ONE barrier per K-step
// (the vmcnt drain at the barrier lands after ds_read+MFMA, hiding load
// latency under compute). XCD-aware bijective block swizzle (m204) so
// panel-sharing tiles colocate on an XCD's L2.
// outbf: 1 = bf16 out to Cb. 2 = bf16 out to Cb with QSCALE folded into
//        columns < 768 (QKV pack for the attention kernel).
// remap 1/2: scatter window rows to image rows (2 = roll +(4,3,3)).
// accum: += into Cf.
__global__ __launch_bounds__(256) void k_gemm_mfma(const ushort_t* __restrict__ A,
                                                   const ushort_t* __restrict__ W,
                                                   const float* __restrict__ bias,
                                                   float* __restrict__ Cf,
                                                   ushort_t* __restrict__ Cb,
                                                   int M, int N, int K,
                                                   int act, int remap, int accum, int outbf) {
    __shared__ ushort_t As[2][128 * 32];
    __shared__ ushort_t Bs[2][128 * 32];
    int tid = threadIdx.x, lane = tid & 63, w = tid >> 6;
    int wm = w >> 1, wn = w & 1;

    // XCD-aware bijective swizzle of the linear block id (m204 formula):
    // hardware round-robins dispatch-order ids across 8 XCDs; remap so each
    // XCD computes a CONTIGUOUS chunk of tiles (shared A/W panels stay in L2).
    int nx = gridDim.x;
    int nwg = nx * gridDim.y;
    int orig = blockIdx.y * nx + blockIdx.x;
    int sq = nwg >> 3, sr = nwg & 7;
    int xcd = orig & 7, sidx = orig >> 3;
    int swz = ((xcd < sr) ? xcd * (sq + 1) : sr * (sq + 1) + (xcd - sr) * sq) + sidx;
    int m0 = (swz / nx) * 128, n0 = (swz % nx) * 128;

    // staging addresses: wave w stages rows [w*32, w*32+32) of A and B.
    // per-lane global src: row = base + lane/4, 16B slot = (lane&3)*16B.
    int rr = lane >> 2, ss = (lane & 3) * 8;
    const ushort_t* gA0 = A + (size_t)(m0 + w * 32 + rr) * K + ss;
    const ushort_t* gA1 = gA0 + (size_t)16 * K;
    const ushort_t* gB0 = W + (size_t)(n0 + w * 32 + rr) * K + ss;
    const ushort_t* gB1 = gB0 + (size_t)16 * K;
    int lb = (w * 32) * 32;              // wave-uniform LDS elem offset

    f32x4 acc[4][4];
#pragma unroll
    for (int mi = 0; mi < 4; ++mi)
#pragma unroll
        for (int ni = 0; ni < 4; ++ni) acc[mi][ni] = (f32x4){0.f, 0.f, 0.f, 0.f};

    int nt = K >> 5;
    // prologue: stage K-step 0 into buf 0
    gload16(gA0, &As[0][lb]);
    gload16(gA1, &As[0][lb + 512]);
    gload16(gB0, &Bs[0][lb]);
    gload16(gB1, &Bs[0][lb + 512]);
    __syncthreads();                     // vmcnt drain -> buf0 ready

    int cur = 0;
    for (int t = 0; t < nt; ++t) {
        if (t + 1 < nt) {                // issue next K-step into the other buf
            int k1 = (t + 1) << 5;
            gload16(gA0 + k1, &As[cur ^ 1][lb]);
            gload16(gA1 + k1, &As[cur ^ 1][lb + 512]);
            gload16(gB0 + k1, &Bs[cur ^ 1][lb]);
            gload16(gB1 + k1, &Bs[cur ^ 1][lb + 512]);
        }
        bf16x8 af[4], bg[4];
#pragma unroll
        for (int mi = 0; mi < 4; ++mi)
            af[mi] = *(const bf16x8*)&As[cur][(wm * 64 + mi * 16 + (lane & 15)) * 32 + (lane >> 4) * 8];
#pragma unroll
        for (int ni = 0; ni < 4; ++ni)
            bg[ni] = *(const bf16x8*)&Bs[cur][(wn * 64 + ni * 16 + (lane & 15)) * 32 + (lane >> 4) * 8];
#pragma unroll
        for (int mi = 0; mi < 4; ++mi)
#pragma unroll
            for (int ni = 0; ni < 4; ++ni)
                acc[mi][ni] = __builtin_amdgcn_mfma_f32_16x16x32_bf16(af[mi], bg[ni], acc[mi][ni], 0, 0, 0);
        __syncthreads();                 // drains vmcnt (next buf staged) + lgkm
        cur ^= 1;
    }

    int cl = lane & 15, rq = lane >> 4;
#pragma unroll
    for (int mi = 0; mi < 4; ++mi) {
#pragma unroll
        for (int ni = 0; ni < 4; ++ni) {
            int gcol = n0 + wn * 64 + ni * 16 + cl;
            float bv = bias[gcol];
#pragma unroll
            for (int i = 0; i < 4; ++i) {
                int r = m0 + wm * 64 + mi * 16 + rq * 4 + i;
                float v = acc[mi][ni][i] + bv;
                if (act) v = gelu_f(v);
                if (outbf) {
                    float sc = (outbf == 2 && gcol < 768) ? QSCALE : 1.0f;
                    Cb[(size_t)r * N + gcol] = f2bf(v * sc);
                } else {
                    size_t orow;
                    if (remap == 0) {
                        orow = (size_t)r * N;
                    } else {
                        int wi = r / NTOK, n = r % NTOK;
                        int b = wi >> 3, rem = wi & 7;
                        int wd = rem >> 2, wh = (rem >> 1) & 1, ww = rem & 1;
                        int dn = n / 49, r2 = n % 49, hn = r2 / 7, wnn = r2 % 7;
                        int d = wd * 8 + dn, h = wh * 7 + hn, ww2 = ww * 7 + wnn;
                        if (remap == 2) { d = (d + 4) & 15; h = (h + 3) % 14; ww2 = (ww2 + 3) % 14; }
                        orow = (size_t)((b * 16 + d) * 196 + h * 14 + ww2) * N;
                    }
                    if (accum) Cf[orow + gcol] += v;
                    else       Cf[orow + gcol] = v;
                }
            }
        }
    }
}

// ---------------------------------------------------------------------------
// f32 GEMM (head c1 only, N=64): 64x64x16 tile, 4x4 microtile.
__global__ __launch_bounds__(256) void k_gemm_f32(const float* __restrict__ A,
                                                  const float* __restrict__ W,
                                                  const float* __restrict__ bias,
                                                  float* __restrict__ C,
                                                  int M, int N, int K, int act) {
    __shared__ float As[16][64];
    __shared__ float Bs[16][64];
    int tid = threadIdx.x;
    int m0 = blockIdx.y * 64, n0 = blockIdx.x * 64;
    int lrow = tid >> 2;
    int lk   = (tid & 3) * 4;
    const float* aptr = A + (size_t)(m0 + lrow) * K + lk;
    const float* wptr = W + (size_t)(n0 + lrow) * K + lk;
    int tx = tid & 15, ty = tid >> 4;
    float acc[4][4] = {};
    for (int kt = 0; kt < K; kt += 16) {
        float4 av = *(const float4*)(aptr + kt);
        float4 wv4 = *(const float4*)(wptr + kt);
        As[lk + 0][lrow] = av.x;  As[lk + 1][lrow] = av.y;
        As[lk + 2][lrow] = av.z;  As[lk + 3][lrow] = av.w;
        Bs[lk + 0][lrow] = wv4.x; Bs[lk + 1][lrow] = wv4.y;
        Bs[lk + 2][lrow] = wv4.z; Bs[lk + 3][lrow] = wv4.w;
        __syncthreads();
#pragma unroll
        for (int k = 0; k < 16; ++k) {
            float4 a = *(const float4*)&As[k][ty * 4];
            float4 b = *(const float4*)&Bs[k][tx * 4];
            float avv[4] = {a.x, a.y, a.z, a.w};
            float bvv[4] = {b.x, b.y, b.z, b.w};
#pragma unroll
            for (int i = 0; i < 4; ++i)
#pragma unroll
                for (int j = 0; j < 4; ++j)
                    acc[i][j] += avv[i] * bvv[j];
        }
        __syncthreads();
    }
    float bvals[4];
#pragma unroll
    for (int j = 0; j < 4; ++j) bvals[j] = bias[n0 + tx * 4 + j];
#pragma unroll
    for (int i = 0; i < 4; ++i) {
        int r = m0 + ty * 4 + i;
#pragma unroll
        for (int j = 0; j < 4; ++j) {
            float v = acc[i][j] + bvals[j];
            if (act) v = gelu_f(v);
            C[(size_t)r * N + n0 + tx * 4 + j] = v;
        }
    }
}

// ---------------------------------------------------------------------------
// MFMA attention (round-1 structure): one block per (window, head), 4 waves.
// QKVb bf16 [token][2304], Q pre-scaled. Bias bf16 [head][392][416] precomputed
// (cols >= 392 are 0). Per wave: q-tiles of 16 rows. QK^T = 26 MFMAs; softmax
// in registers; unnormalized P (bf16) -> per-wave full-row LDS tile ->
// PV = 13x2 MFMAs; 1/sum applied at output. No block barrier in main loop
// (P buffers wave-private). Strides chosen conflict-free (<=2-way).
__global__ __launch_bounds__(256) void k_attn_mfma(const ushort_t* __restrict__ QKVb,
                                                   const ushort_t* __restrict__ Bias,
                                                   ushort_t* __restrict__ AO,
                                                   int shifted) {
    __shared__ int      Lrid[NTOK];            // shift-mask region id per token
    __shared__ ushort_t Ks[NTOK * KS_ST];      // K  [key][d], stride 40
    __shared__ ushort_t Vs[32 * VS_ST];        // V^T [d][key], stride 456, pad keys 0
    __shared__ ushort_t Ps[4][16 * PS_ST];     // per-wave P tile [q16][key 0..415]

    int wi   = blockIdx.x / NHEADS;
    int head = blockIdx.x % NHEADS;
    int wbase = wi * NTOK;
    int tid = threadIdx.x, lane = tid & 63, wv = tid >> 6;
    int cl = lane & 15, g = lane >> 4;
    const ushort_t* QW = QKVb + (size_t)wbase * 2304;

    // ---- stage K [392][40] and V^T [32][456]
    for (int idx = tid; idx < NTOK * 4; idx += 256) {
        int j = idx >> 2, d8 = (idx & 3) * 8;
        const ushort_t* rowp = QW + (size_t)j * 2304 + head * 32 + d8;
        bf16x8 kv = *(const bf16x8*)(rowp + 768);
        *(bf16x8*)&Ks[j * KS_ST + d8] = kv;
        bf16x8 vv = *(const bf16x8*)(rowp + 1536);
#pragma unroll
        for (int t = 0; t < 8; ++t)
            Vs[(d8 + t) * VS_ST + j] = (ushort_t)vv[t];
    }
    // zero V^T pad keys 392..415
    for (int idx = tid; idx < 32 * 24; idx += 256) {
        int d = idx / 24, jj = idx - d * 24;
        Vs[d * VS_ST + 392 + jj] = 0;
    }
    // region ids for shift mask
    if (shifted) {
        int rem = wi & 7;
        int wd = rem >> 2, wh = (rem >> 1) & 1, ww = rem & 1;
        for (int idx = tid; idx < NTOK; idx += 256) {
            int dn = idx / 49, r2 = idx % 49, hn = r2 / 7, wn = r2 % 7;
            int d = wd * 8 + dn, h = wh * 7 + hn, w = ww * 7 + wn;
            Lrid[idx] = (((d < 8) ? 0 : (d < 12 ? 1 : 2)) * 3 +
                         ((h < 7) ? 0 : (h < 11 ? 1 : 2))) * 3 +
                         ((w < 7) ? 0 : (w < 11 ? 1 : 2));
        }
    }
    __syncthreads();

    ushort_t* Pw = Ps[wv];
    const ushort_t* Bh = Bias + (size_t)head * 392 * 416;

    for (int qt = wv; qt < NQT; qt += 4) {
        // Q fragment (A-frag): row = cl (clamped), k-slice = g*8.
        int qrow = qt * 16 + cl; if (qrow > 391) qrow = 391;
        bf16x8 qfrag = *(const bf16x8*)(QW + (size_t)qrow * 2304 + head * 32 + g * 8);

        // ---- QK^T: 26 tiles, one MFMA each
        f32x4 acc[NKT];
#pragma unroll
        for (int kt = 0; kt < NKT; ++kt) {
            int krow = kt * 16 + cl; if (krow > 391) krow = 391;
            bf16x8 kfrag = *(const bf16x8*)&Ks[krow * KS_ST + g * 8];
            acc[kt] = __builtin_amdgcn_mfma_f32_16x16x32_bf16(
                qfrag, kfrag, (f32x4){0.f, 0.f, 0.f, 0.f}, 0, 0, 0);
        }

        // ---- precomputed bias + shift mask + pad mask, running row max
        int qc[4], ridq[4];
        float mrow[4];
#pragma unroll
        for (int i = 0; i < 4; ++i) {
            int qg = qt * 16 + g * 4 + i;
            qc[i] = qg > 391 ? 391 : qg;
            ridq[i] = shifted ? Lrid[qc[i]] : 0;
            mrow[i] = -1e30f;
        }
#pragma unroll
        for (int kt = 0; kt < NKT; ++kt) {
            int key = kt * 16 + cl;
            int kc = key > 391 ? 391 : key;
            int ridk = shifted ? Lrid[kc] : 0;
            bool pad = key > 391;
#pragma unroll
            for (int i = 0; i < 4; ++i) {
                float s = acc[kt][i] + bf2f(Bh[(size_t)qc[i] * 416 + key]);
                if (shifted && ridk != ridq[i]) s -= 100.0f;
                if (pad) s = -1e30f;
                acc[kt][i] = s;
                mrow[i] = fmaxf(mrow[i], s);
            }
        }
        // row max across the 16 lanes holding the row (offsets stay in-group)
#pragma unroll
        for (int off = 1; off < 16; off <<= 1)
#pragma unroll
            for (int i = 0; i < 4; ++i)
                mrow[i] = fmaxf(mrow[i], __shfl_xor(mrow[i], off));

        // ---- exp, row sum, write unnormalized P (bf16) to wave-private LDS
        float srow[4] = {0.f, 0.f, 0.f, 0.f};
#pragma unroll
        for (int kt = 0; kt < NKT; ++kt) {
            int key = kt * 16 + cl;
#pragma unroll
            for (int i = 0; i < 4; ++i) {
                float p = __expf(acc[kt][i] - mrow[i]);
                srow[i] += p;
                Pw[(g * 4 + i) * PS_ST + key] = f2bf(p);
            }
        }
#pragma unroll
        for (int off = 1; off < 16; off <<= 1)
#pragma unroll
            for (int i = 0; i < 4; ++i)
                srow[i] += __shfl_xor(srow[i], off);

        __threadfence_block();   // order cross-lane P write -> P read (wave lockstep)

        // ---- PV: O[16q x 32d] = P[16 x 416] @ V[416 x 32]; 13 k-chunks x 2 d-tiles
        f32x4 out0 = (f32x4){0.f, 0.f, 0.f, 0.f};
        f32x4 out1 = (f32x4){0.f, 0.f, 0.f, 0.f};
#pragma unroll
        for (int c = 0; c < 13; ++c) {
            int ko = c * 32 + g * 8;
            bf16x8 pfrag = *(const bf16x8*)&Pw[cl * PS_ST + ko];
            bf16x8 v0 = *(const bf16x8*)&Vs[cl * VS_ST + ko];
            bf16x8 v1 = *(const bf16x8*)&Vs[(16 + cl) * VS_ST + ko];
            out0 = __builtin_amdgcn_mfma_f32_16x16x32_bf16(pfrag, v0, out0, 0, 0, 0);
            out1 = __builtin_amdgcn_mfma_f32_16x16x32_bf16(pfrag, v1, out1, 0, 0, 0);
        }

        // ---- normalize by 1/sum and write bf16 output (window-ordered rows)
#pragma unroll
        for (int i = 0; i < 4; ++i) {
            float inv = 1.0f / srow[i];
            int qg = qt * 16 + g * 4 + i;
            if (qg < NTOK) {
                size_t ob = (size_t)(wbase + qg) * CDIM + head * 32;
                AO[ob + cl]      = f2bf(out0[i] * inv);
                AO[ob + 16 + cl] = f2bf(out1[i] * inv);
            }
        }
    }
}

// ---------------------------------------------------------------------------
__global__ __launch_bounds__(256) void k_head_c2(const float* __restrict__ Y64,
                                                 const float* __restrict__ w2,
                                                 const float* __restrict__ b2,
                                                 float* __restrict__ O2) {
    int idx = blockIdx.x * 256 + threadIdx.x;
    if (idx >= T_TOK * 2) return;
    int t = idx >> 1, p = idx & 1;
    const float* yr = Y64 + (size_t)t * 64;
    float acc = b2[p];
#pragma unroll
    for (int o = 0; o < 64; ++o) acc += yr[o] * w2[p * 64 + o];
    O2[idx] = gelu_f(acc);
}

__global__ __launch_bounds__(256) void k_final(const float* __restrict__ O2,
                                               float* __restrict__ out) {
    int idx = blockIdx.x * 256 + threadIdx.x;
    if (idx >= 2 * 2 * 3136) return;
    int b = idx / 6272;
    int p = (idx / 3136) & 1;
    int s = idx % 3136;
    int t = b * 3136 + s;
    out[idx] = O2[t * 2 + p] * O2[(size_t)T_TOK * 2 + t * 2 + p];
}

// ---------------------------------------------------------------------------
extern "C" void kernel_launch(void* const* d_in, const int* in_sizes, int n_in,
                              void* d_out, int out_size, void* d_ws, size_t ws_size,
                              hipStream_t stream) {
    const float* x     = (const float*)d_in[0];
    const float* n1_g  = (const float*)d_in[1];
    const float* n1_b  = (const float*)d_in[2];
    const float* qkv_w = (const float*)d_in[3];
    const float* qkv_b = (const float*)d_in[4];
    const float* proj_w= (const float*)d_in[5];
    const float* proj_b= (const float*)d_in[6];
    const float* rpb   = (const float*)d_in[7];
    const float* n2_g  = (const float*)d_in[8];
    const float* n2_b  = (const float*)d_in[9];
    const float* fc1_w = (const float*)d_in[10];
    const float* fc1_b = (const float*)d_in[11];
    const float* fc2_w = (const float*)d_in[12];
    const float* fc2_b = (const float*)d_in[13];
    const float* hln_g = (const float*)d_in[14];
    const float* hln_b = (const float*)d_in[15];
    const float* c1_w  = (const float*)d_in[16];
    const float* c1_b  = (const float*)d_in[17];
    const float* c2_w  = (const float*)d_in[18];
    const float* c2_b  = (const float*)d_in[19];
    const int*   rpi   = (const int*)d_in[20];

    // ws: X f32 | BIG f32 (QKV bf16 pack; bf16 mlp-hidden overlay) |
    //     Y64 (rpbT overlay) | O2 | XWb bf16 | WB bf16 (WB1/WB2 = Bias overlay)
    float* ws   = (float*)d_ws;
    float* X    = ws;                                  // 4,816,896 f32
    float* BIG  = X + (size_t)T_TOK * CDIM;            // 14,450,688 f32
    float* Y64  = BIG + (size_t)T_TOK * 2304;          // 401,408 f32
    float* O2   = Y64 + (size_t)T_TOK * 64;            // 25,088 f32
    ushort_t* XWb = (ushort_t*)(O2 + 2 * T_TOK * 2);
    ushort_t* WB  = XWb + (size_t)T_TOK * CDIM;
    ushort_t* WBq = WB;
    ushort_t* WBp = WBq + (size_t)2304 * 768;
    ushort_t* WB1 = WBp + (size_t)768 * 768;
    ushort_t* WB2 = WB1 + (size_t)3072 * 768;
    ushort_t* BIGb = (ushort_t*)BIG;                   // bf16 mlp hidden overlay
    ushort_t* QKVb = (ushort_t*)BIG;                   // bf16 QKV pack overlay
    ushort_t* BiasT = WB1;                             // bf16 bias table overlay (7.83MB <= WB1+WB2)
    float* rpbT = Y64;                                 // 60,840 f32 overlay (Y64 free until head)

    const int NQ = 2304 * 768, NP = 768 * 768, N1 = 3072 * 768, N2 = 768 * 3072;

    for (int br = 0; br < 2; ++br) {
        k_transpose_in<<<dim3(98, 24, 2), dim3(32, 8), 0, stream>>>(x, X);
        for (int bl = 0; bl < 2; ++bl) {
            int pb = br * 2 + bl;
            int shifted = bl;
            // weight conversion f32 -> bf16 (qkv/proj now; fc1/fc2 after attention,
            // since their region holds the bias table during attention)
            k_f2b<<<(NQ / 4 + 255) / 256, 256, 0, stream>>>(qkv_w + (size_t)pb * NQ, WBq, NQ / 4);
            k_f2b<<<(NP / 4 + 255) / 256, 256, 0, stream>>>(proj_w + (size_t)pb * NP, WBp, NP / 4);

            // bias table precompute: rpbT then Bias[24][392][416]
            k_rpbT<<<(24 * 2535 + 255) / 256, 256, 0, stream>>>(rpb + (size_t)pb * 2535 * 24, rpbT);
            k_bias<<<24 * 392, 256, 0, stream>>>(rpbT, rpi, BiasT);

            k_ln_bf<<<T_TOK, 256, 0, stream>>>(X, XWb, n1_g + pb * 768, n1_b + pb * 768, shifted ? 2 : 1);
            // QKV GEMM -> bf16 pack (Q pre-scaled by QSCALE)
            k_gemm_mfma<<<dim3(18, 49), 256, 0, stream>>>(XWb, WBq, qkv_b + pb * 2304,
                                                          (float*)0, QKVb,
                                                          T_TOK, 2304, 768, 0, 0, 0, 2);
            k_attn_mfma<<<NWIN * NHEADS, 256, 0, stream>>>(QKVb, BiasT, XWb, shifted);

            // fc weights now (bias table dead)
            k_f2b<<<(N1 / 4 + 255) / 256, 256, 0, stream>>>(fc1_w + (size_t)pb * N1, WB1, N1 / 4);
            k_f2b<<<(N2 / 4 + 255) / 256, 256, 0, stream>>>(fc2_w + (size_t)pb * N2, WB2, N2 / 4);

            k_gemm_mfma<<<dim3(6, 49), 256, 0, stream>>>(XWb, WBp, proj_b + pb * 768,
                                                         X, (ushort_t*)0,
                                                         T_TOK, 768, 768, 0, shifted ? 2 : 1, 1, 0);
            k_ln_bf<<<T_TOK, 256, 0, stream>>>(X, XWb, n2_g + pb * 768, n2_b + pb * 768, 0);
            k_gemm_mfma<<<dim3(24, 49), 256, 0, stream>>>(XWb, WB1, fc1_b + pb * 3072,
                                                          (float*)0, BIGb,
                                                          T_TOK, 3072, 768, 1, 0, 0, 1);
            k_gemm_mfma<<<dim3(6, 49), 256, 0, stream>>>(BIGb, WB2, fc2_b + pb * 768,
                                                         X, (ushort_t*)0,
                                                         T_TOK, 768, 3072, 0, 0, 1, 0);
        }
        // head: all f32 (BIG free here, reuse for LN output)
        k_ln_f32<<<T_TOK, 256, 0, stream>>>(X, BIG, hln_g + br * 768, hln_b + br * 768);
        k_gemm_f32<<<dim3(1, 98), 256, 0, stream>>>(BIG, c1_w + (size_t)br * 64 * 768,
                                                    c1_b + br * 64, Y64,
                                                    T_TOK, 64, 768, 1);
        k_head_c2<<<(T_TOK * 2 + 255) / 256, 256, 0, stream>>>(Y64, c2_w + br * 128, c2_b + br * 2,
                                                               O2 + (size_t)br * T_TOK * 2);
    }
    k_final<<<(2 * 2 * 3136 + 255) / 256, 256, 0, stream>>>(O2, (float*)d_out);
}

// Round 6
// 1781.824 us; speedup vs baseline: 1.1055x; 1.1055x over previous
//
#include <hip/hip_runtime.h>
#include <hip/hip_bf16.h>

// Problem constants
#define T_TOK 6272      // B*D*H*W tokens (2*16*14*14)
#define CDIM  768
#define NTOK  392       // tokens per window (8*7*7)
#define NWIN  16        // total windows (B=2 * 8)
#define NHEADS 24
#define HDIM  32
#define QSCALE 0.17677669529663687f  // 32^-0.5

// attention MFMA geometry
#define NKT 26          // key tiles of 16 -> 416 (keys 392..415 masked via bias)
#define NQT 25          // query tiles of 16 -> 400 (rows >=392 clamped, not written)
#define KS_ST 40        // K LDS row stride (elems): 80B -> conflict-free b128 col reads
#define VS_ST 456       // V^T LDS row stride (elems); key slot XOR'd by (d&24)
#define PS_ST 424       // P LDS row stride (elems): 848B, 16B-aligned rows

typedef unsigned short ushort_t;
typedef __attribute__((ext_vector_type(8))) short bf16x8;
typedef __attribute__((ext_vector_type(4))) short bf16x4;
typedef __attribute__((ext_vector_type(4))) float f32x4;

__device__ __forceinline__ float bf2f(ushort_t h) {
    union { unsigned int u; float f; } v; v.u = ((unsigned int)h) << 16; return v.f;
}
__device__ __forceinline__ ushort_t f2bf(float f) {
    return __bfloat16_as_ushort(__float2bfloat16(f));
}
__device__ __forceinline__ float gelu_f(float x) {
    return 0.5f * x * (1.0f + erff(x * 0.70710678118654752f));
}

// async global->LDS, 16B per lane. LDS dest is wave-uniform base; HW writes
// lane i at base + i*16B. Global src is per-lane.
__device__ __forceinline__ void gload16(const ushort_t* g, ushort_t* l) {
    __builtin_amdgcn_global_load_lds(
        (const __attribute__((address_space(1))) void*)g,
        (__attribute__((address_space(3))) void*)l,
        16, 0, 0);
}

// ---------------------------------------------------------------------------
// (B,C,D,H,W) f32 -> X[t][c] f32
__global__ __launch_bounds__(256) void k_transpose_in(const float* __restrict__ x,
                                                      float* __restrict__ X) {
    __shared__ float tile[32][33];
    int b  = blockIdx.z;
    int s0 = blockIdx.x * 32, c0 = blockIdx.y * 32;
    int tx = threadIdx.x, ty = threadIdx.y;
#pragma unroll
    for (int r = 0; r < 4; ++r)
        tile[ty + r * 8][tx] = x[((size_t)b * 768 + c0 + ty + r * 8) * 3136 + s0 + tx];
    __syncthreads();
#pragma unroll
    for (int r = 0; r < 4; ++r)
        X[((size_t)b * 3136 + s0 + ty + r * 8) * 768 + c0 + tx] = tile[tx][ty + r * 8];
}

// ---------------------------------------------------------------------------
// f32 -> bf16 elementwise, 4 elems/thread (n must be multiple of 4)
__global__ __launch_bounds__(256) void k_f2b(const float* __restrict__ s,
                                             ushort_t* __restrict__ d, int n4) {
    int i = blockIdx.x * 256 + threadIdx.x;
    if (i >= n4) return;
    float4 v = ((const float4*)s)[i];
    bf16x4 r;
    r[0] = (short)f2bf(v.x); r[1] = (short)f2bf(v.y);
    r[2] = (short)f2bf(v.z); r[3] = (short)f2bf(v.w);
    *(bf16x4*)&d[(size_t)i * 4] = r;
}

// ---------------------------------------------------------------------------
// rpb [2535][24] f32 -> rpbT [24][2535] f32
__global__ __launch_bounds__(256) void k_rpbT(const float* __restrict__ rpb,
                                              float* __restrict__ rpbT) {
    int idx = blockIdx.x * 256 + threadIdx.x;
    if (idx >= 24 * 2535) return;
    int h = idx / 2535, r = idx - h * 2535;
    rpbT[idx] = rpb[(size_t)r * 24 + h];
}

// Bias2 in MFMA C-fragment order: Bias2[h][qt][kt][lane][i] bf16, where the
// attn lane (cl=lane&15, g=lane>>4) reads its 4 values (rows qt*16+g*4+i,
// col kt*16+cl) as ONE 8B load. Pad cols (>=392) = -1e30 (masks via softmax).
// Rows >= 392 clamped to 391 (outputs never written). One block per (h,qt).
__global__ __launch_bounds__(256) void k_bias(const float* __restrict__ rpbT,
                                              const int* __restrict__ rpi,
                                              ushort_t* __restrict__ Bias2) {
    int blk = blockIdx.x;            // h*25 + qt
    int h = blk / 25, qt = blk - h * 25;
    const float* rp = rpbT + (size_t)h * 2535;
    int t = threadIdx.x;
    int i = t & 3, l = t >> 2;       // l = consumer lane
    int cl = l & 15, g = l >> 4;
    int row = qt * 16 + g * 4 + i; if (row > 391) row = 391;
    ushort_t* out = Bias2 + (size_t)blk * 26 * 256;
    const int* ri = rpi + (size_t)row * NTOK;
#pragma unroll
    for (int kt = 0; kt < 26; ++kt) {
        int col = kt * 16 + cl;
        float v = (col < NTOK) ? rp[ri[col]] : -1e30f;
        out[kt * 256 + t] = f2bf(v);
    }
}

// ---------------------------------------------------------------------------
// LayerNorm, bf16 output. mode 0: identity rows. mode 1: window-gather.
// mode 2: window-gather with roll(-4,-3,-3) folded in.
__global__ __launch_bounds__(256) void k_ln_bf(const float* __restrict__ X,
                                               ushort_t* __restrict__ Y,
                                               const float* __restrict__ g,
                                               const float* __restrict__ bta,
                                               int mode) {
    int row = blockIdx.x;
    int src = row;
    if (mode != 0) {
        int wi = row / NTOK, n = row % NTOK;
        int b = wi >> 3, rem = wi & 7;
        int wd = rem >> 2, wh = (rem >> 1) & 1, ww = rem & 1;
        int dn = n / 49, r2 = n % 49, hn = r2 / 7, wn = r2 % 7;
        int d = wd * 8 + dn, h = wh * 7 + hn, w = ww * 7 + wn;
        if (mode == 2) { d = (d + 4) & 15; h = (h + 3) % 14; w = (w + 3) % 14; }
        src = (b * 16 + d) * 196 + h * 14 + w;
    }
    const float* xr = X + (size_t)src * CDIM;
    int tid = threadIdx.x;
    float v0 = xr[tid], v1 = xr[tid + 256], v2 = xr[tid + 512];
    float s = v0 + v1 + v2;
    float q = v0 * v0 + v1 * v1 + v2 * v2;
    __shared__ float red[8];
#pragma unroll
    for (int off = 32; off > 0; off >>= 1) {
        s += __shfl_down(s, off);
        q += __shfl_down(q, off);
    }
    int lane = tid & 63, wv = tid >> 6;
    if (lane == 0) { red[wv] = s; red[4 + wv] = q; }
    __syncthreads();
    float ts = red[0] + red[1] + red[2] + red[3];
    float tq = red[4] + red[5] + red[6] + red[7];
    float mu  = ts * (1.0f / 768.0f);
    float var = tq * (1.0f / 768.0f) - mu * mu;
    float rstd = rsqrtf(var + 1e-5f);
    ushort_t* yr = Y + (size_t)row * CDIM;
    yr[tid]       = f2bf((v0 - mu) * rstd * g[tid]       + bta[tid]);
    yr[tid + 256] = f2bf((v1 - mu) * rstd * g[tid + 256] + bta[tid + 256]);
    yr[tid + 512] = f2bf((v2 - mu) * rstd * g[tid + 512] + bta[tid + 512]);
}

// LayerNorm, f32 output, identity rows (head path only).
__global__ __launch_bounds__(256) void k_ln_f32(const float* __restrict__ X,
                                                float* __restrict__ Y,
                                                const float* __restrict__ g,
                                                const float* __restrict__ bta) {
    int row = blockIdx.x, tid = threadIdx.x;
    const float* xr = X + (size_t)row * CDIM;
    float v0 = xr[tid], v1 = xr[tid + 256], v2 = xr[tid + 512];
    float s = v0 + v1 + v2;
    float q = v0 * v0 + v1 * v1 + v2 * v2;
    __shared__ float red[8];
#pragma unroll
    for (int off = 32; off > 0; off >>= 1) {
        s += __shfl_down(s, off);
        q += __shfl_down(q, off);
    }
    int lane = tid & 63, wv = tid >> 6;
    if (lane == 0) { red[wv] = s; red[4 + wv] = q; }
    __syncthreads();
    float ts = red[0] + red[1] + red[2] + red[3];
    float tq = red[4] + red[5] + red[6] + red[7];
    float mu  = ts * (1.0f / 768.0f);
    float var = tq * (1.0f / 768.0f) - mu * mu;
    float rstd = rsqrtf(var + 1e-5f);
    float* yr = Y + (size_t)row * CDIM;
    yr[tid]       = (v0 - mu) * rstd * g[tid]       + bta[tid];
    yr[tid + 256] = (v1 - mu) * rstd * g[tid + 256] + bta[tid + 256];
    yr[tid + 512] = (v2 - mu) * rstd * g[tid + 512] + bta[tid + 512];
}

// ---------------------------------------------------------------------------
// MFMA GEMM: C[M,N] = act(A[M,K] @ W[N,K]^T + bias)
// 128x128 tile, BK=32, 4 waves; global_load_lds width=16, double-buffered
// 2-phase (one barrier/K-step); XCD-aware bijective block swizzle (m204).
__global__ __launch_bounds__(256) void k_gemm_mfma(const ushort_t* __restrict__ A,
                                                   const ushort_t* __restrict__ W,
                                                   const float* __restrict__ bias,
                                                   float* __restrict__ Cf,
                                                   ushort_t* __restrict__ Cb,
                                                   int M, int N, int K,
                                                   int act, int remap, int accum, int outbf) {
    __shared__ ushort_t As[2][128 * 32];
    __shared__ ushort_t Bs[2][128 * 32];
    int tid = threadIdx.x, lane = tid & 63, w = tid >> 6;
    int wm = w >> 1, wn = w & 1;

    int nx = gridDim.x;
    int nwg = nx * gridDim.y;
    int orig = blockIdx.y * nx + blockIdx.x;
    int sq = nwg >> 3, sr = nwg & 7;
    int xcd = orig & 7, sidx = orig >> 3;
    int swz = ((xcd < sr) ? xcd * (sq + 1) : sr * (sq + 1) + (xcd - sr) * sq) + sidx;
    int m0 = (swz / nx) * 128, n0 = (swz % nx) * 128;

    int rr = lane >> 2, ss = (lane & 3) * 8;
    const ushort_t* gA0 = A + (size_t)(m0 + w * 32 + rr) * K + ss;
    const ushort_t* gA1 = gA0 + (size_t)16 * K;
    const ushort_t* gB0 = W + (size_t)(n0 + w * 32 + rr) * K + ss;
    const ushort_t* gB1 = gB0 + (size_t)16 * K;
    int lb = (w * 32) * 32;              // wave-uniform LDS elem offset

    f32x4 acc[4][4];
#pragma unroll
    for (int mi = 0; mi < 4; ++mi)
#pragma unroll
        for (int ni = 0; ni < 4; ++ni) acc[mi][ni] = (f32x4){0.f, 0.f, 0.f, 0.f};

    int nt = K >> 5;
    gload16(gA0, &As[0][lb]);
    gload16(gA1, &As[0][lb + 512]);
    gload16(gB0, &Bs[0][lb]);
    gload16(gB1, &Bs[0][lb + 512]);
    __syncthreads();                     // vmcnt drain -> buf0 ready

    int cur = 0;
    for (int t = 0; t < nt; ++t) {
        if (t + 1 < nt) {
            int k1 = (t + 1) << 5;
            gload16(gA0 + k1, &As[cur ^ 1][lb]);
            gload16(gA1 + k1, &As[cur ^ 1][lb + 512]);
            gload16(gB0 + k1, &Bs[cur ^ 1][lb]);
            gload16(gB1 + k1, &Bs[cur ^ 1][lb + 512]);
        }
        bf16x8 af[4], bg[4];
#pragma unroll
        for (int mi = 0; mi < 4; ++mi)
            af[mi] = *(const bf16x8*)&As[cur][(wm * 64 + mi * 16 + (lane & 15)) * 32 + (lane >> 4) * 8];
#pragma unroll
        for (int ni = 0; ni < 4; ++ni)
            bg[ni] = *(const bf16x8*)&Bs[cur][(wn * 64 + ni * 16 + (lane & 15)) * 32 + (lane >> 4) * 8];
#pragma unroll
        for (int mi = 0; mi < 4; ++mi)
#pragma unroll
            for (int ni = 0; ni < 4; ++ni)
                acc[mi][ni] = __builtin_amdgcn_mfma_f32_16x16x32_bf16(af[mi], bg[ni], acc[mi][ni], 0, 0, 0);
        __syncthreads();
        cur ^= 1;
    }

    int cl = lane & 15, rq = lane >> 4;
#pragma unroll
    for (int mi = 0; mi < 4; ++mi) {
#pragma unroll
        for (int ni = 0; ni < 4; ++ni) {
            int gcol = n0 + wn * 64 + ni * 16 + cl;
            float bv = bias[gcol];
#pragma unroll
            for (int i = 0; i < 4; ++i) {
                int r = m0 + wm * 64 + mi * 16 + rq * 4 + i;
                float v = acc[mi][ni][i] + bv;
                if (act) v = gelu_f(v);
                if (outbf) {
                    float sc = (outbf == 2 && gcol < 768) ? QSCALE : 1.0f;
                    Cb[(size_t)r * N + gcol] = f2bf(v * sc);
                } else {
                    size_t orow;
                    if (remap == 0) {
                        orow = (size_t)r * N;
                    } else {
                        int wi = r / NTOK, n = r % NTOK;
                        int b = wi >> 3, rem = wi & 7;
                        int wd = rem >> 2, wh = (rem >> 1) & 1, ww = rem & 1;
                        int dn = n / 49, r2 = n % 49, hn = r2 / 7, wnn = r2 % 7;
                        int d = wd * 8 + dn, h = wh * 7 + hn, ww2 = ww * 7 + wnn;
                        if (remap == 2) { d = (d + 4) & 15; h = (h + 3) % 14; ww2 = (ww2 + 3) % 14; }
                        orow = (size_t)((b * 16 + d) * 196 + h * 14 + ww2) * N;
                    }
                    if (accum) Cf[orow + gcol] += v;
                    else       Cf[orow + gcol] = v;
                }
            }
        }
    }
}

// ---------------------------------------------------------------------------
// f32 GEMM (head c1 only, N=64): 64x64x16 tile, 4x4 microtile.
__global__ __launch_bounds__(256) void k_gemm_f32(const float* __restrict__ A,
                                                  const float* __restrict__ W,
                                                  const float* __restrict__ bias,
                                                  float* __restrict__ C,
                                                  int M, int N, int K, int act) {
    __shared__ float As[16][64];
    __shared__ float Bs[16][64];
    int tid = threadIdx.x;
    int m0 = blockIdx.y * 64, n0 = blockIdx.x * 64;
    int lrow = tid >> 2;
    int lk   = (tid & 3) * 4;
    const float* aptr = A + (size_t)(m0 + lrow) * K + lk;
    const float* wptr = W + (size_t)(n0 + lrow) * K + lk;
    int tx = tid & 15, ty = tid >> 4;
    float acc[4][4] = {};
    for (int kt = 0; kt < K; kt += 16) {
        float4 av = *(const float4*)(aptr + kt);
        float4 wv4 = *(const float4*)(wptr + kt);
        As[lk + 0][lrow] = av.x;  As[lk + 1][lrow] = av.y;
        As[lk + 2][lrow] = av.z;  As[lk + 3][lrow] = av.w;
        Bs[lk + 0][lrow] = wv4.x; Bs[lk + 1][lrow] = wv4.y;
        Bs[lk + 2][lrow] = wv4.z; Bs[lk + 3][lrow] = wv4.w;
        __syncthreads();
#pragma unroll
        for (int k = 0; k < 16; ++k) {
            float4 a = *(const float4*)&As[k][ty * 4];
            float4 b = *(const float4*)&Bs[k][tx * 4];
            float avv[4] = {a.x, a.y, a.z, a.w};
            float bvv[4] = {b.x, b.y, b.z, b.w};
#pragma unroll
            for (int i = 0; i < 4; ++i)
#pragma unroll
                for (int j = 0; j < 4; ++j)
                    acc[i][j] += avv[i] * bvv[j];
        }
        __syncthreads();
    }
    float bvals[4];
#pragma unroll
    for (int j = 0; j < 4; ++j) bvals[j] = bias[n0 + tx * 4 + j];
#pragma unroll
    for (int i = 0; i < 4; ++i) {
        int r = m0 + ty * 4 + i;
#pragma unroll
        for (int j = 0; j < 4; ++j) {
            float v = acc[i][j] + bvals[j];
            if (act) v = gelu_f(v);
            C[(size_t)r * N + n0 + tx * 4 + j] = v;
        }
    }
}

// ---------------------------------------------------------------------------
// MFMA attention v3: 768 blocks (= 3 * 256 CUs exactly), each block =
// (window, head, half-of-q-tiles). Block id decoded so window wi lands on
// XCD wi>>1, matching the QKV GEMM's swizzled write placement (L2 locality).
// Bias2 in C-fragment order: one 8B load per (kt) per lane (pad folded as
// -1e30). V^T staged with key-slot XOR (d&24): write banks 4t+{0,4,8,12},
// conflict-free; PV b128 reads stay 16B-aligned (XOR is a multiple of 8).
__global__ __launch_bounds__(256) void k_attn_mfma(const ushort_t* __restrict__ QKVb,
                                                   const ushort_t* __restrict__ Bias2,
                                                   ushort_t* __restrict__ AO,
                                                   int shifted) {
    __shared__ int      Lrid[NTOK];            // shift-mask region id per token
    __shared__ ushort_t Ks[NTOK * KS_ST];      // K  [key][d], stride 40
    __shared__ ushort_t Vs[32 * VS_ST];        // V^T [d][slot], slot = key ^ (d&24)
    __shared__ ushort_t Ps[4][16 * PS_ST];     // per-wave P tile [q16][key 0..415]

    // decode: x = target XCD, head, wlow, half; wi = 2*x + wlow
    int bid = blockIdx.x;
    int x = bid & 7, rdec = bid >> 3;
    int head = rdec % 24;
    int z = rdec / 24;                 // 0..3
    int wi = x * 2 + (z & 1);
    int half = z >> 1;
    int wbase = wi * NTOK;
    int tid = threadIdx.x, lane = tid & 63, wv = tid >> 6;
    int cl = lane & 15, g = lane >> 4;
    const ushort_t* QW = QKVb + (size_t)wbase * 2304;

    // ---- stage K [392][40] and V^T [32][456] (XOR'd key slots)
    for (int idx = tid; idx < NTOK * 4; idx += 256) {
        int j = idx >> 2, d8 = (idx & 3) * 8;
        const ushort_t* rowp = QW + (size_t)j * 2304 + head * 32 + d8;
        bf16x8 kv = *(const bf16x8*)(rowp + 768);
        *(bf16x8*)&Ks[j * KS_ST + d8] = kv;
        bf16x8 vv = *(const bf16x8*)(rowp + 1536);
        int js = j ^ d8;               // (d8+t)&24 == d8 for t<8
#pragma unroll
        for (int t = 0; t < 8; ++t)
            Vs[(d8 + t) * VS_ST + js] = (ushort_t)vv[t];
    }
    // zero V^T pad keys 392..415 (same XOR mapping)
    for (int idx = tid; idx < 32 * 24; idx += 256) {
        int d = idx / 24, jj = idx - d * 24;
        Vs[d * VS_ST + ((392 + jj) ^ (d & 24))] = 0;
    }
    // region ids for shift mask
    if (shifted) {
        int rem = wi & 7;
        int wd = rem >> 2, wh = (rem >> 1) & 1, ww = rem & 1;
        for (int idx = tid; idx < NTOK; idx += 256) {
            int dn = idx / 49, r2 = idx % 49, hn = r2 / 7, wn = r2 % 7;
            int d = wd * 8 + dn, h = wh * 7 + hn, w = ww * 7 + wn;
            Lrid[idx] = (((d < 8) ? 0 : (d < 12 ? 1 : 2)) * 3 +
                         ((h < 7) ? 0 : (h < 11 ? 1 : 2))) * 3 +
                         ((w < 7) ? 0 : (w < 11 ? 1 : 2));
        }
    }
    __syncthreads();

    ushort_t* Pw = Ps[wv];
    const ushort_t* Bh = Bias2 + (size_t)head * 25 * 26 * 256;
    int vm0 = cl & 24, vm1 = (16 + cl) & 24;   // V slot XOR masks for d=cl, 16+cl

    int qend = half ? NQT : 13;
    for (int qt = (half ? 13 : 0) + wv; qt < qend; qt += 4) {
        // Q fragment (A-frag): row = cl (clamped), k-slice = g*8.
        int qrow = qt * 16 + cl; if (qrow > 391) qrow = 391;
        bf16x8 qfrag = *(const bf16x8*)(QW + (size_t)qrow * 2304 + head * 32 + g * 8);

        // ---- QK^T: 26 tiles, one MFMA each
        f32x4 acc[NKT];
#pragma unroll
        for (int kt = 0; kt < NKT; ++kt) {
            int krow = kt * 16 + cl; if (krow > 391) krow = 391;
            bf16x8 kfrag = *(const bf16x8*)&Ks[krow * KS_ST + g * 8];
            acc[kt] = __builtin_amdgcn_mfma_f32_16x16x32_bf16(
                qfrag, kfrag, (f32x4){0.f, 0.f, 0.f, 0.f}, 0, 0, 0);
        }

        // ---- bias (one 8B C-fragment-ordered load per kt) + shift mask
        const ushort_t* Bq = Bh + (size_t)qt * 26 * 256;
        int qc[4], ridq[4];
        float mrow[4];
#pragma unroll
        for (int i = 0; i < 4; ++i) {
            int qg = qt * 16 + g * 4 + i;
            qc[i] = qg > 391 ? 391 : qg;
            ridq[i] = shifted ? Lrid[qc[i]] : 0;
            mrow[i] = -1e30f;
        }
#pragma unroll
        for (int kt = 0; kt < NKT; ++kt) {
            bf16x4 b4 = *(const bf16x4*)&Bq[kt * 256 + lane * 4];
            int key = kt * 16 + cl;
            int kc = key > 391 ? 391 : key;
            int ridk = shifted ? Lrid[kc] : 0;
#pragma unroll
            for (int i = 0; i < 4; ++i) {
                float s = acc[kt][i] + bf2f((ushort_t)b4[i]);
                if (shifted && ridk != ridq[i]) s -= 100.0f;
                acc[kt][i] = s;
                mrow[i] = fmaxf(mrow[i], s);
            }
        }
        // row max across the 16 lanes holding the row (offsets stay in-group)
#pragma unroll
        for (int off = 1; off < 16; off <<= 1)
#pragma unroll
            for (int i = 0; i < 4; ++i)
                mrow[i] = fmaxf(mrow[i], __shfl_xor(mrow[i], off));

        // ---- exp, row sum, write unnormalized P (bf16) to wave-private LDS
        float srow[4] = {0.f, 0.f, 0.f, 0.f};
#pragma unroll
        for (int kt = 0; kt < NKT; ++kt) {
            int key = kt * 16 + cl;
#pragma unroll
            for (int i = 0; i < 4; ++i) {
                float p = __expf(acc[kt][i] - mrow[i]);
                srow[i] += p;
                Pw[(g * 4 + i) * PS_ST + key] = f2bf(p);
            }
        }
#pragma unroll
        for (int off = 1; off < 16; off <<= 1)
#pragma unroll
            for (int i = 0; i < 4; ++i)
                srow[i] += __shfl_xor(srow[i], off);

        __threadfence_block();   // order cross-lane P write -> P read (wave lockstep)

        // ---- PV: O[16q x 32d] = P[16 x 416] @ V[416 x 32]; 13 k-chunks x 2 d-tiles
        f32x4 out0 = (f32x4){0.f, 0.f, 0.f, 0.f};
        f32x4 out1 = (f32x4){0.f, 0.f, 0.f, 0.f};
#pragma unroll
        for (int c = 0; c < 13; ++c) {
            int ko = c * 32 + g * 8;
            bf16x8 pfrag = *(const bf16x8*)&Pw[cl * PS_ST + ko];
            bf16x8 v0 = *(const bf16x8*)&Vs[cl * VS_ST + (ko ^ vm0)];
            bf16x8 v1 = *(const bf16x8*)&Vs[(16 + cl) * VS_ST + (ko ^ vm1)];
            out0 = __builtin_amdgcn_mfma_f32_16x16x32_bf16(pfrag, v0, out0, 0, 0, 0);
            out1 = __builtin_amdgcn_mfma_f32_16x16x32_bf16(pfrag, v1, out1, 0, 0, 0);
        }

        // ---- normalize by 1/sum and write bf16 output (window-ordered rows)
#pragma unroll
        for (int i = 0; i < 4; ++i) {
            float inv = 1.0f / srow[i];
            int qg = qt * 16 + g * 4 + i;
            if (qg < NTOK) {
                size_t ob = (size_t)(wbase + qg) * CDIM + head * 32;
                AO[ob + cl]      = f2bf(out0[i] * inv);
                AO[ob + 16 + cl] = f2bf(out1[i] * inv);
            }
        }
    }
}

// ---------------------------------------------------------------------------
__global__ __launch_bounds__(256) void k_head_c2(const float* __restrict__ Y64,
                                                 const float* __restrict__ w2,
                                                 const float* __restrict__ b2,
                                                 float* __restrict__ O2) {
    int idx = blockIdx.x * 256 + threadIdx.x;
    if (idx >= T_TOK * 2) return;
    int t = idx >> 1, p = idx & 1;
    const float* yr = Y64 + (size_t)t * 64;
    float acc = b2[p];
#pragma unroll
    for (int o = 0; o < 64; ++o) acc += yr[o] * w2[p * 64 + o];
    O2[idx] = gelu_f(acc);
}

__global__ __launch_bounds__(256) void k_final(const float* __restrict__ O2,
                                               float* __restrict__ out) {
    int idx = blockIdx.x * 256 + threadIdx.x;
    if (idx >= 2 * 2 * 3136) return;
    int b = idx / 6272;
    int p = (idx / 3136) & 1;
    int s = idx % 3136;
    int t = b * 3136 + s;
    out[idx] = O2[t * 2 + p] * O2[(size_t)T_TOK * 2 + t * 2 + p];
}

// ---------------------------------------------------------------------------
extern "C" void kernel_launch(void* const* d_in, const int* in_sizes, int n_in,
                              void* d_out, int out_size, void* d_ws, size_t ws_size,
                              hipStream_t stream) {
    const float* x     = (const float*)d_in[0];
    const float* n1_g  = (const float*)d_in[1];
    const float* n1_b  = (const float*)d_in[2];
    const float* qkv_w = (const float*)d_in[3];
    const float* qkv_b = (const float*)d_in[4];
    const float* proj_w= (const float*)d_in[5];
    const float* proj_b= (const float*)d_in[6];
    const float* rpb   = (const float*)d_in[7];
    const float* n2_g  = (const float*)d_in[8];
    const float* n2_b  = (const float*)d_in[9];
    const float* fc1_w = (const float*)d_in[10];
    const float* fc1_b = (const float*)d_in[11];
    const float* fc2_w = (const float*)d_in[12];
    const float* fc2_b = (const float*)d_in[13];
    const float* hln_g = (const float*)d_in[14];
    const float* hln_b = (const float*)d_in[15];
    const float* c1_w  = (const float*)d_in[16];
    const float* c1_b  = (const float*)d_in[17];
    const float* c2_w  = (const float*)d_in[18];
    const float* c2_b  = (const float*)d_in[19];
    const int*   rpi   = (const int*)d_in[20];

    // ws: X f32 | BIG f32 (QKV bf16 pack; bf16 mlp-hidden overlay) |
    //     Y64 (rpbT overlay) | O2 | XWb bf16 | WB bf16 (WB1/WB2 = Bias2 overlay)
    float* ws   = (float*)d_ws;
    float* X    = ws;                                  // 4,816,896 f32
    float* BIG  = X + (size_t)T_TOK * CDIM;            // 14,450,688 f32
    float* Y64  = BIG + (size_t)T_TOK * 2304;          // 401,408 f32
    float* O2   = Y64 + (size_t)T_TOK * 64;            // 25,088 f32
    ushort_t* XWb = (ushort_t*)(O2 + 2 * T_TOK * 2);
    ushort_t* WB  = XWb + (size_t)T_TOK * CDIM;
    ushort_t* WBq = WB;
    ushort_t* WBp = WBq + (size_t)2304 * 768;
    ushort_t* WB1 = WBp + (size_t)768 * 768;
    ushort_t* WB2 = WB1 + (size_t)3072 * 768;
    ushort_t* BIGb = (ushort_t*)BIG;                   // bf16 mlp hidden overlay
    ushort_t* QKVb = (ushort_t*)BIG;                   // bf16 QKV pack overlay
    ushort_t* BiasT = WB1;                             // Bias2 overlay: 7.99MB <= 9.44MB
    float* rpbT = Y64;                                 // 60,840 f32 overlay (Y64 free until head)

    const int NQ = 2304 * 768, NP = 768 * 768, N1 = 3072 * 768, N2 = 768 * 3072;

    for (int br = 0; br < 2; ++br) {
        k_transpose_in<<<dim3(98, 24, 2), dim3(32, 8), 0, stream>>>(x, X);
        for (int bl = 0; bl < 2; ++bl) {
            int pb = br * 2 + bl;
            int shifted = bl;
            // weight conversion f32 -> bf16 (qkv/proj now; fc1/fc2 after attention,
            // since their region holds the bias table during attention)
            k_f2b<<<(NQ / 4 + 255) / 256, 256, 0, stream>>>(qkv_w + (size_t)pb * NQ, WBq, NQ / 4);
            k_f2b<<<(NP / 4 + 255) / 256, 256, 0, stream>>>(proj_w + (size_t)pb * NP, WBp, NP / 4);

            // bias table precompute: rpbT then Bias2[24][25][26][256]
            k_rpbT<<<(24 * 2535 + 255) / 256, 256, 0, stream>>>(rpb + (size_t)pb * 2535 * 24, rpbT);
            k_bias<<<24 * 25, 256, 0, stream>>>(rpbT, rpi, BiasT);

            k_ln_bf<<<T_TOK, 256, 0, stream>>>(X, XWb, n1_g + pb * 768, n1_b + pb * 768, shifted ? 2 : 1);
            // QKV GEMM -> bf16 pack (Q pre-scaled by QSCALE)
            k_gemm_mfma<<<dim3(18, 49), 256, 0, stream>>>(XWb, WBq, qkv_b + pb * 2304,
                                                          (float*)0, QKVb,
                                                          T_TOK, 2304, 768, 0, 0, 0, 2);
            k_attn_mfma<<<NWIN * NHEADS * 2, 256, 0, stream>>>(QKVb, BiasT, XWb, shifted);

            // fc weights now (bias table dead)
            k_f2b<<<(N1 / 4 + 255) / 256, 256, 0, stream>>>(fc1_w + (size_t)pb * N1, WB1, N1 / 4);
            k_f2b<<<(N2 / 4 + 255) / 256, 256, 0, stream>>>(fc2_w + (size_t)pb * N2, WB2, N2 / 4);

            k_gemm_mfma<<<dim3(6, 49), 256, 0, stream>>>(XWb, WBp, proj_b + pb * 768,
                                                         X, (ushort_t*)0,
                                                         T_TOK, 768, 768, 0, shifted ? 2 : 1, 1, 0);
            k_ln_bf<<<T_TOK, 256, 0, stream>>>(X, XWb, n2_g + pb * 768, n2_b + pb * 768, 0);
            k_gemm_mfma<<<dim3(24, 49), 256, 0, stream>>>(XWb, WB1, fc1_b + pb * 3072,
                                                          (float*)0, BIGb,
                                                          T_TOK, 3072, 768, 1, 0, 0, 1);
            k_gemm_mfma<<<dim3(6, 49), 256, 0, stream>>>(BIGb, WB2, fc2_b + pb * 768,
                                                         X, (ushort_t*)0,
                                                         T_TOK, 768, 3072, 0, 0, 1, 0);
        }
        // head: all f32 (BIG free here, reuse for LN output)
        k_ln_f32<<<T_TOK, 256, 0, stream>>>(X, BIG, hln_g + br * 768, hln_b + br * 768);
        k_gemm_f32<<<dim3(1, 98), 256, 0, stream>>>(BIG, c1_w + (size_t)br * 64 * 768,
                                                    c1_b + br * 64, Y64,
                                                    T_TOK, 64, 768, 1);
        k_head_c2<<<(T_TOK * 2 + 255) / 256, 256, 0, stream>>>(Y64, c2_w + br * 128, c2_b + br * 2,
                                                               O2 + (size_t)br * T_TOK * 2);
    }
    k_final<<<(2 * 2 * 3136 + 255) / 256, 256, 0, stream>>>(O2, (float*)d_out);
}

// Round 7
// 1747.823 us; speedup vs baseline: 1.1270x; 1.0195x over previous
//
#include <hip/hip_runtime.h>
#include <hip/hip_bf16.h>

// Problem constants
#define T_TOK 6272      // B*D*H*W tokens (2*16*14*14)
#define CDIM  768
#define NTOK  392      // tokens per window (8*7*7)
#define NWIN  16        // total windows (B=2 * 8)
#define NHEADS 24
#define HDIM  32
#define QSCALE 0.17677669529663687f  // 32^-0.5

// attention MFMA geometry
#define NKT 26          // key tiles of 16 -> 416 (keys 392..415 masked via bias)
#define NQT 25          // query tiles of 16 -> 400 (rows >=392 clamped, not written)
#define KS_ST 40        // K LDS row stride (elems): 80B -> conflict-free b128 col reads
#define VS_ST 456       // V^T LDS row stride (elems); key slot XOR'd by (d&24)
#define PS_ST 424       // P LDS row stride (elems): 848B, 16B-aligned rows

typedef unsigned short ushort_t;
typedef __attribute__((ext_vector_type(8))) short bf16x8;
typedef __attribute__((ext_vector_type(4))) short bf16x4;
typedef __attribute__((ext_vector_type(4))) float f32x4;

__device__ __forceinline__ float bf2f(ushort_t h) {
    union { unsigned int u; float f; } v; v.u = ((unsigned int)h) << 16; return v.f;
}
__device__ __forceinline__ ushort_t f2bf(float f) {
    return __bfloat16_as_ushort(__float2bfloat16(f));
}
__device__ __forceinline__ float gelu_f(float x) {
    return 0.5f * x * (1.0f + erff(x * 0.70710678118654752f));
}

// async global->LDS, 16B per lane. LDS dest is wave-uniform base; HW writes
// lane i at base + i*16B. Global src is per-lane.
__device__ __forceinline__ void gload16(const ushort_t* g, ushort_t* l) {
    __builtin_amdgcn_global_load_lds(
        (const __attribute__((address_space(1))) void*)g,
        (__attribute__((address_space(3))) void*)l,
        16, 0, 0);
}

// ---------------------------------------------------------------------------
// (B,C,D,H,W) f32 -> X[t][c] f32
__global__ __launch_bounds__(256) void k_transpose_in(const float* __restrict__ x,
                                                      float* __restrict__ X) {
    __shared__ float tile[32][33];
    int b  = blockIdx.z;
    int s0 = blockIdx.x * 32, c0 = blockIdx.y * 32;
    int tx = threadIdx.x, ty = threadIdx.y;
#pragma unroll
    for (int r = 0; r < 4; ++r)
        tile[ty + r * 8][tx] = x[((size_t)b * 768 + c0 + ty + r * 8) * 3136 + s0 + tx];
    __syncthreads();
#pragma unroll
    for (int r = 0; r < 4; ++r)
        X[((size_t)b * 3136 + s0 + ty + r * 8) * 768 + c0 + tx] = tile[tx][ty + r * 8];
}

// ---------------------------------------------------------------------------
// f32 -> bf16 elementwise, 4 elems/thread (n must be multiple of 4)
__global__ __launch_bounds__(256) void k_f2b(const float* __restrict__ s,
                                             ushort_t* __restrict__ d, int n4) {
    int i = blockIdx.x * 256 + threadIdx.x;
    if (i >= n4) return;
    float4 v = ((const float4*)s)[i];
    bf16x4 r;
    r[0] = (short)f2bf(v.x); r[1] = (short)f2bf(v.y);
    r[2] = (short)f2bf(v.z); r[3] = (short)f2bf(v.w);
    *(bf16x4*)&d[(size_t)i * 4] = r;
}

// ---------------------------------------------------------------------------
// rpb [2535][24] f32 -> rpbT [24][2535] f32
__global__ __launch_bounds__(256) void k_rpbT(const float* __restrict__ rpb,
                                              float* __restrict__ rpbT) {
    int idx = blockIdx.x * 256 + threadIdx.x;
    if (idx >= 24 * 2535) return;
    int h = idx / 2535, r = idx - h * 2535;
    rpbT[idx] = rpb[(size_t)r * 24 + h];
}

// Bias2 in MFMA C-fragment order: Bias2[h][qt][kt][lane][i] bf16, where the
// attn lane (cl=lane&15, g=lane>>4) reads its 4 values (rows qt*16+g*4+i,
// col kt*16+cl) as ONE 8B load. Pad cols (>=392) = -1e30 (masks via softmax).
// Rows >= 392 clamped to 391 (outputs never written). One block per (h,qt).
__global__ __launch_bounds__(256) void k_bias(const float* __restrict__ rpbT,
                                              const int* __restrict__ rpi,
                                              ushort_t* __restrict__ Bias2) {
    int blk = blockIdx.x;            // h*25 + qt
    int h = blk / 25, qt = blk - h * 25;
    const float* rp = rpbT + (size_t)h * 2535;
    int t = threadIdx.x;
    int i = t & 3, l = t >> 2;       // l = consumer lane
    int cl = l & 15, g = l >> 4;
    int row = qt * 16 + g * 4 + i; if (row > 391) row = 391;
    ushort_t* out = Bias2 + (size_t)blk * 26 * 256;
    const int* ri = rpi + (size_t)row * NTOK;
#pragma unroll
    for (int kt = 0; kt < 26; ++kt) {
        int col = kt * 16 + cl;
        float v = (col < NTOK) ? rp[ri[col]] : -1e30f;
        out[kt * 256 + t] = f2bf(v);
    }
}

// ---------------------------------------------------------------------------
// LayerNorm, bf16 output. mode 0: identity rows. mode 1: window-gather.
// mode 2: window-gather with roll(-4,-3,-3) folded in.
__global__ __launch_bounds__(256) void k_ln_bf(const float* __restrict__ X,
                                               ushort_t* __restrict__ Y,
                                               const float* __restrict__ g,
                                               const float* __restrict__ bta,
                                               int mode) {
    int row = blockIdx.x;
    int src = row;
    if (mode != 0) {
        int wi = row / NTOK, n = row % NTOK;
        int b = wi >> 3, rem = wi & 7;
        int wd = rem >> 2, wh = (rem >> 1) & 1, ww = rem & 1;
        int dn = n / 49, r2 = n % 49, hn = r2 / 7, wn = r2 % 7;
        int d = wd * 8 + dn, h = wh * 7 + hn, w = ww * 7 + wn;
        if (mode == 2) { d = (d + 4) & 15; h = (h + 3) % 14; w = (w + 3) % 14; }
        src = (b * 16 + d) * 196 + h * 14 + w;
    }
    const float* xr = X + (size_t)src * CDIM;
    int tid = threadIdx.x;
    float v0 = xr[tid], v1 = xr[tid + 256], v2 = xr[tid + 512];
    float s = v0 + v1 + v2;
    float q = v0 * v0 + v1 * v1 + v2 * v2;
    __shared__ float red[8];
#pragma unroll
    for (int off = 32; off > 0; off >>= 1) {
        s += __shfl_down(s, off);
        q += __shfl_down(q, off);
    }
    int lane = tid & 63, wv = tid >> 6;
    if (lane == 0) { red[wv] = s; red[4 + wv] = q; }
    __syncthreads();
    float ts = red[0] + red[1] + red[2] + red[3];
    float tq = red[4] + red[5] + red[6] + red[7];
    float mu  = ts * (1.0f / 768.0f);
    float var = tq * (1.0f / 768.0f) - mu * mu;
    float rstd = rsqrtf(var + 1e-5f);
    ushort_t* yr = Y + (size_t)row * CDIM;
    yr[tid]       = f2bf((v0 - mu) * rstd * g[tid]       + bta[tid]);
    yr[tid + 256] = f2bf((v1 - mu) * rstd * g[tid + 256] + bta[tid + 256]);
    yr[tid + 512] = f2bf((v2 - mu) * rstd * g[tid + 512] + bta[tid + 512]);
}

// LayerNorm, f32 output, identity rows (head path only).
__global__ __launch_bounds__(256) void k_ln_f32(const float* __restrict__ X,
                                                float* __restrict__ Y,
                                                const float* __restrict__ g,
                                                const float* __restrict__ bta) {
    int row = blockIdx.x, tid = threadIdx.x;
    const float* xr = X + (size_t)row * CDIM;
    float v0 = xr[tid], v1 = xr[tid + 256], v2 = xr[tid + 512];
    float s = v0 + v1 + v2;
    float q = v0 * v0 + v1 * v1 + v2 * v2;
    __shared__ float red[8];
#pragma unroll
    for (int off = 32; off > 0; off >>= 1) {
        s += __shfl_down(s, off);
        q += __shfl_down(q, off);
    }
    int lane = tid & 63, wv = tid >> 6;
    if (lane == 0) { red[wv] = s; red[4 + wv] = q; }
    __syncthreads();
    float ts = red[0] + red[1] + red[2] + red[3];
    float tq = red[4] + red[5] + red[6] + red[7];
    float mu  = ts * (1.0f / 768.0f);
    float var = tq * (1.0f / 768.0f) - mu * mu;
    float rstd = rsqrtf(var + 1e-5f);
    float* yr = Y + (size_t)row * CDIM;
    yr[tid]       = (v0 - mu) * rstd * g[tid]       + bta[tid];
    yr[tid + 256] = (v1 - mu) * rstd * g[tid + 256] + bta[tid + 256];
    yr[tid + 512] = (v2 - mu) * rstd * g[tid + 512] + bta[tid + 512];
}

// ---------------------------------------------------------------------------
// MFMA GEMM: C[M,N] = act(A[M,K] @ W[N,K]^T + bias)
// 128x128 tile, BK=32, 4 waves; global_load_lds width=16.
// DEPTH-2 pipeline (3 LDS buffers) with COUNTED vmcnt (T4, m218 pattern):
// per K-step: issue loads for t+2 -> s_waitcnt vmcnt(8) (own 4 loads for cur
// done; 8 younger stay in flight) -> s_barrier (cross-wave staging visible)
// -> ds_read+MFMA -> s_barrier (WAR: buffer t+2 was read at t-1). Tail drains
// 8 -> 4 -> 0. Never vmcnt(0) in steady state. XCD-aware bijective swizzle.
__global__ __launch_bounds__(256) void k_gemm_mfma(const ushort_t* __restrict__ A,
                                                   const ushort_t* __restrict__ W,
                                                   const float* __restrict__ bias,
                                                   float* __restrict__ Cf,
                                                   ushort_t* __restrict__ Cb,
                                                   int M, int N, int K,
                                                   int act, int remap, int accum, int outbf) {
    __shared__ ushort_t As[3][128 * 32];
    __shared__ ushort_t Bs[3][128 * 32];
    int tid = threadIdx.x, lane = tid & 63, w = tid >> 6;
    int wm = w >> 1, wn = w & 1;

    int nx = gridDim.x;
    int nwg = nx * gridDim.y;
    int orig = blockIdx.y * nx + blockIdx.x;
    int sq = nwg >> 3, sr = nwg & 7;
    int xcd = orig & 7, sidx = orig >> 3;
    int swz = ((xcd < sr) ? xcd * (sq + 1) : sr * (sq + 1) + (xcd - sr) * sq) + sidx;
    int m0 = (swz / nx) * 128, n0 = (swz % nx) * 128;

    int rr = lane >> 2, ss = (lane & 3) * 8;
    const ushort_t* gA0 = A + (size_t)(m0 + w * 32 + rr) * K + ss;
    const ushort_t* gA1 = gA0 + (size_t)16 * K;
    const ushort_t* gB0 = W + (size_t)(n0 + w * 32 + rr) * K + ss;
    const ushort_t* gB1 = gB0 + (size_t)16 * K;
    int lb = (w * 32) * 32;              // wave-uniform LDS elem offset

    f32x4 acc[4][4];
#pragma unroll
    for (int mi = 0; mi < 4; ++mi)
#pragma unroll
        for (int ni = 0; ni < 4; ++ni) acc[mi][ni] = (f32x4){0.f, 0.f, 0.f, 0.f};

    int nt = K >> 5;
    // prologue: stage K-steps 0 and 1 into buffers 0,1 (8 loads/wave in flight)
    gload16(gA0, &As[0][lb]);
    gload16(gA1, &As[0][lb + 512]);
    gload16(gB0, &Bs[0][lb]);
    gload16(gB1, &Bs[0][lb + 512]);
    gload16(gA0 + 32, &As[1][lb]);
    gload16(gA1 + 32, &As[1][lb + 512]);
    gload16(gB0 + 32, &Bs[1][lb]);
    gload16(gB1 + 32, &Bs[1][lb + 512]);

    int cur = 0;
    for (int t = 0; t < nt; ++t) {
        if (t + 2 < nt) {
            int kk = (t + 2) << 5;
            int nb = cur + 2; if (nb >= 3) nb -= 3;
            gload16(gA0 + kk, &As[nb][lb]);
            gload16(gA1 + kk, &As[nb][lb + 512]);
            gload16(gB0 + kk, &Bs[nb][lb]);
            gload16(gB1 + kk, &Bs[nb][lb + 512]);
            asm volatile("s_waitcnt vmcnt(8)" ::: "memory");
        } else if (t + 1 < nt) {
            asm volatile("s_waitcnt vmcnt(4)" ::: "memory");
        } else {
            asm volatile("s_waitcnt vmcnt(0)" ::: "memory");
        }
        __builtin_amdgcn_s_barrier();    // staging of buf[cur] visible to all
        bf16x8 af[4], bg[4];
#pragma unroll
        for (int mi = 0; mi < 4; ++mi)
            af[mi] = *(const bf16x8*)&As[cur][(wm * 64 + mi * 16 + (lane & 15)) * 32 + (lane >> 4) * 8];
#pragma unroll
        for (int ni = 0; ni < 4; ++ni)
            bg[ni] = *(const bf16x8*)&Bs[cur][(wn * 64 + ni * 16 + (lane & 15)) * 32 + (lane >> 4) * 8];
#pragma unroll
        for (int mi = 0; mi < 4; ++mi)
#pragma unroll
            for (int ni = 0; ni < 4; ++ni)
                acc[mi][ni] = __builtin_amdgcn_mfma_f32_16x16x32_bf16(af[mi], bg[ni], acc[mi][ni], 0, 0, 0);
        __builtin_amdgcn_s_barrier();    // all reads of buf[cur] done (WAR guard)
        cur = (cur + 1 == 3) ? 0 : cur + 1;
    }

    int cl = lane & 15, rq = lane >> 4;
#pragma unroll
    for (int mi = 0; mi < 4; ++mi) {
#pragma unroll
        for (int ni = 0; ni < 4; ++ni) {
            int gcol = n0 + wn * 64 + ni * 16 + cl;
            float bv = bias[gcol];
#pragma unroll
            for (int i = 0; i < 4; ++i) {
                int r = m0 + wm * 64 + mi * 16 + rq * 4 + i;
                float v = acc[mi][ni][i] + bv;
                if (act) v = gelu_f(v);
                if (outbf) {
                    float sc = (outbf == 2 && gcol < 768) ? QSCALE : 1.0f;
                    Cb[(size_t)r * N + gcol] = f2bf(v * sc);
                } else {
                    size_t orow;
                    if (remap == 0) {
                        orow = (size_t)r * N;
                    } else {
                        int wi = r / NTOK, n = r % NTOK;
                        int b = wi >> 3, rem = wi & 7;
                        int wd = rem >> 2, wh = (rem >> 1) & 1, ww = rem & 1;
                        int dn = n / 49, r2 = n % 49, hn = r2 / 7, wnn = r2 % 7;
                        int d = wd * 8 + dn, h = wh * 7 + hn, ww2 = ww * 7 + wnn;
                        if (remap == 2) { d = (d + 4) & 15; h = (h + 3) % 14; ww2 = (ww2 + 3) % 14; }
                        orow = (size_t)((b * 16 + d) * 196 + h * 14 + ww2) * N;
                    }
                    if (accum) Cf[orow + gcol] += v;
                    else       Cf[orow + gcol] = v;
                }
            }
        }
    }
}

// ---------------------------------------------------------------------------
// f32 GEMM (head c1 only, N=64): 64x64x16 tile, 4x4 microtile.
__global__ __launch_bounds__(256) void k_gemm_f32(const float* __restrict__ A,
                                                  const float* __restrict__ W,
                                                  const float* __restrict__ bias,
                                                  float* __restrict__ C,
                                                  int M, int N, int K, int act) {
    __shared__ float As[16][64];
    __shared__ float Bs[16][64];
    int tid = threadIdx.x;
    int m0 = blockIdx.y * 64, n0 = blockIdx.x * 64;
    int lrow = tid >> 2;
    int lk   = (tid & 3) * 4;
    const float* aptr = A + (size_t)(m0 + lrow) * K + lk;
    const float* wptr = W + (size_t)(n0 + lrow) * K + lk;
    int tx = tid & 15, ty = tid >> 4;
    float acc[4][4] = {};
    for (int kt = 0; kt < K; kt += 16) {
        float4 av = *(const float4*)(aptr + kt);
        float4 wv4 = *(const float4*)(wptr + kt);
        As[lk + 0][lrow] = av.x;  As[lk + 1][lrow] = av.y;
        As[lk + 2][lrow] = av.z;  As[lk + 3][lrow] = av.w;
        Bs[lk + 0][lrow] = wv4.x; Bs[lk + 1][lrow] = wv4.y;
        Bs[lk + 2][lrow] = wv4.z; Bs[lk + 3][lrow] = wv4.w;
        __syncthreads();
#pragma unroll
        for (int k = 0; k < 16; ++k) {
            float4 a = *(const float4*)&As[k][ty * 4];
            float4 b = *(const float4*)&Bs[k][tx * 4];
            float avv[4] = {a.x, a.y, a.z, a.w};
            float bvv[4] = {b.x, b.y, b.z, b.w};
#pragma unroll
            for (int i = 0; i < 4; ++i)
#pragma unroll
                for (int j = 0; j < 4; ++j)
                    acc[i][j] += avv[i] * bvv[j];
        }
        __syncthreads();
    }
    float bvals[4];
#pragma unroll
    for (int j = 0; j < 4; ++j) bvals[j] = bias[n0 + tx * 4 + j];
#pragma unroll
    for (int i = 0; i < 4; ++i) {
        int r = m0 + ty * 4 + i;
#pragma unroll
        for (int j = 0; j < 4; ++j) {
            float v = acc[i][j] + bvals[j];
            if (act) v = gelu_f(v);
            C[(size_t)r * N + n0 + tx * 4 + j] = v;
        }
    }
}

// ---------------------------------------------------------------------------
// MFMA attention v3: 768 blocks (= 3 * 256 CUs exactly), each block =
// (window, head, half-of-q-tiles). Block id decoded so window wi lands on
// XCD wi>>1, matching the QKV GEMM's swizzled write placement (L2 locality).
// Bias2 in C-fragment order: one 8B load per (kt) per lane (pad folded as
// -1e30). V^T staged with key-slot XOR (d&24): write banks 4t+{0,4,8,12},
// conflict-free; PV b128 reads stay 16B-aligned (XOR is a multiple of 8).
__global__ __launch_bounds__(256) void k_attn_mfma(const ushort_t* __restrict__ QKVb,
                                                   const ushort_t* __restrict__ Bias2,
                                                   ushort_t* __restrict__ AO,
                                                   int shifted) {
    __shared__ int      Lrid[NTOK];            // shift-mask region id per token
    __shared__ ushort_t Ks[NTOK * KS_ST];      // K  [key][d], stride 40
    __shared__ ushort_t Vs[32 * VS_ST];        // V^T [d][slot], slot = key ^ (d&24)
    __shared__ ushort_t Ps[4][16 * PS_ST];     // per-wave P tile [q16][key 0..415]

    // decode: x = target XCD, head, wlow, half; wi = 2*x + wlow
    int bid = blockIdx.x;
    int x = bid & 7, rdec = bid >> 3;
    int head = rdec % 24;
    int z = rdec / 24;                 // 0..3
    int wi = x * 2 + (z & 1);
    int half = z >> 1;
    int wbase = wi * NTOK;
    int tid = threadIdx.x, lane = tid & 63, wv = tid >> 6;
    int cl = lane & 15, g = lane >> 4;
    const ushort_t* QW = QKVb + (size_t)wbase * 2304;

    // ---- stage K [392][40] and V^T [32][456] (XOR'd key slots)
    for (int idx = tid; idx < NTOK * 4; idx += 256) {
        int j = idx >> 2, d8 = (idx & 3) * 8;
        const ushort_t* rowp = QW + (size_t)j * 2304 + head * 32 + d8;
        bf16x8 kv = *(const bf16x8*)(rowp + 768);
        *(bf16x8*)&Ks[j * KS_ST + d8] = kv;
        bf16x8 vv = *(const bf16x8*)(rowp + 1536);
        int js = j ^ d8;               // (d8+t)&24 == d8 for t<8
#pragma unroll
        for (int t = 0; t < 8; ++t)
            Vs[(d8 + t) * VS_ST + js] = (ushort_t)vv[t];
    }
    // zero V^T pad keys 392..415 (same XOR mapping)
    for (int idx = tid; idx < 32 * 24; idx += 256) {
        int d = idx / 24, jj = idx - d * 24;
        Vs[d * VS_ST + ((392 + jj) ^ (d & 24))] = 0;
    }
    // region ids for shift mask
    if (shifted) {
        int rem = wi & 7;
        int wd = rem >> 2, wh = (rem >> 1) & 1, ww = rem & 1;
        for (int idx = tid; idx < NTOK; idx += 256) {
            int dn = idx / 49, r2 = idx % 49, hn = r2 / 7, wn = r2 % 7;
            int d = wd * 8 + dn, h = wh * 7 + hn, w = ww * 7 + wn;
            Lrid[idx] = (((d < 8) ? 0 : (d < 12 ? 1 : 2)) * 3 +
                         ((h < 7) ? 0 : (h < 11 ? 1 : 2))) * 3 +
                         ((w < 7) ? 0 : (w < 11 ? 1 : 2));
        }
    }
    __syncthreads();

    ushort_t* Pw = Ps[wv];
    const ushort_t* Bh = Bias2 + (size_t)head * 25 * 26 * 256;
    int vm0 = cl & 24, vm1 = (16 + cl) & 24;   // V slot XOR masks for d=cl, 16+cl

    int qend = half ? NQT : 13;
    for (int qt = (half ? 13 : 0) + wv; qt < qend; qt += 4) {
        // Q fragment (A-frag): row = cl (clamped), k-slice = g*8.
        int qrow = qt * 16 + cl; if (qrow > 391) qrow = 391;
        bf16x8 qfrag = *(const bf16x8*)(QW + (size_t)qrow * 2304 + head * 32 + g * 8);

        // ---- QK^T: 26 tiles, one MFMA each
        f32x4 acc[NKT];
#pragma unroll
        for (int kt = 0; kt < NKT; ++kt) {
            int krow = kt * 16 + cl; if (krow > 391) krow = 391;
            bf16x8 kfrag = *(const bf16x8*)&Ks[krow * KS_ST + g * 8];
            acc[kt] = __builtin_amdgcn_mfma_f32_16x16x32_bf16(
                qfrag, kfrag, (f32x4){0.f, 0.f, 0.f, 0.f}, 0, 0, 0);
        }

        // ---- bias (one 8B C-fragment-ordered load per kt) + shift mask
        const ushort_t* Bq = Bh + (size_t)qt * 26 * 256;
        int qc[4], ridq[4];
        float mrow[4];
#pragma unroll
        for (int i = 0; i < 4; ++i) {
            int qg = qt * 16 + g * 4 + i;
            qc[i] = qg > 391 ? 391 : qg;
            ridq[i] = shifted ? Lrid[qc[i]] : 0;
            mrow[i] = -1e30f;
        }
#pragma unroll
        for (int kt = 0; kt < NKT; ++kt) {
            bf16x4 b4 = *(const bf16x4*)&Bq[kt * 256 + lane * 4];
            int key = kt * 16 + cl;
            int kc = key > 391 ? 391 : key;
            int ridk = shifted ? Lrid[kc] : 0;
#pragma unroll
            for (int i = 0; i < 4; ++i) {
                float s = acc[kt][i] + bf2f((ushort_t)b4[i]);
                if (shifted && ridk != ridq[i]) s -= 100.0f;
                acc[kt][i] = s;
                mrow[i] = fmaxf(mrow[i], s);
            }
        }
        // row max across the 16 lanes holding the row (offsets stay in-group)
#pragma unroll
        for (int off = 1; off < 16; off <<= 1)
#pragma unroll
            for (int i = 0; i < 4; ++i)
                mrow[i] = fmaxf(mrow[i], __shfl_xor(mrow[i], off));

        // ---- exp, row sum, write unnormalized P (bf16) to wave-private LDS
        float srow[4] = {0.f, 0.f, 0.f, 0.f};
#pragma unroll
        for (int kt = 0; kt < NKT; ++kt) {
            int key = kt * 16 + cl;
#pragma unroll
            for (int i = 0; i < 4; ++i) {
                float p = __expf(acc[kt][i] - mrow[i]);
                srow[i] += p;
                Pw[(g * 4 + i) * PS_ST + key] = f2bf(p);
            }
        }
#pragma unroll
        for (int off = 1; off < 16; off <<= 1)
#pragma unroll
            for (int i = 0; i < 4; ++i)
                srow[i] += __shfl_xor(srow[i], off);

        __threadfence_block();   // order cross-lane P write -> P read (wave lockstep)

        // ---- PV: O[16q x 32d] = P[16 x 416] @ V[416 x 32]; 13 k-chunks x 2 d-tiles
        f32x4 out0 = (f32x4){0.f, 0.f, 0.f, 0.f};
        f32x4 out1 = (f32x4){0.f, 0.f, 0.f, 0.f};
#pragma unroll
        for (int c = 0; c < 13; ++c) {
            int ko = c * 32 + g * 8;
            bf16x8 pfrag = *(const bf16x8*)&Pw[cl * PS_ST + ko];
            bf16x8 v0 = *(const bf16x8*)&Vs[cl * VS_ST + (ko ^ vm0)];
            bf16x8 v1 = *(const bf16x8*)&Vs[(16 + cl) * VS_ST + (ko ^ vm1)];
            out0 = __builtin_amdgcn_mfma_f32_16x16x32_bf16(pfrag, v0, out0, 0, 0, 0);
            out1 = __builtin_amdgcn_mfma_f32_16x16x32_bf16(pfrag, v1, out1, 0, 0, 0);
        }

        // ---- normalize by 1/sum and write bf16 output (window-ordered rows)
#pragma unroll
        for (int i = 0; i < 4; ++i) {
            float inv = 1.0f / srow[i];
            int qg = qt * 16 + g * 4 + i;
            if (qg < NTOK) {
                size_t ob = (size_t)(wbase + qg) * CDIM + head * 32;
                AO[ob + cl]      = f2bf(out0[i] * inv);
                AO[ob + 16 + cl] = f2bf(out1[i] * inv);
            }
        }
    }
}

// ---------------------------------------------------------------------------
__global__ __launch_bounds__(256) void k_head_c2(const float* __restrict__ Y64,
                                                 const float* __restrict__ w2,
                                                 const float* __restrict__ b2,
                                                 float* __restrict__ O2) {
    int idx = blockIdx.x * 256 + threadIdx.x;
    if (idx >= T_TOK * 2) return;
    int t = idx >> 1, p = idx & 1;
    const float* yr = Y64 + (size_t)t * 64;
    float acc = b2[p];
#pragma unroll
    for (int o = 0; o < 64; ++o) acc += yr[o] * w2[p * 64 + o];
    O2[idx] = gelu_f(acc);
}

__global__ __launch_bounds__(256) void k_final(const float* __restrict__ O2,
                                               float* __restrict__ out) {
    int idx = blockIdx.x * 256 + threadIdx.x;
    if (idx >= 2 * 2 * 3136) return;
    int b = idx / 6272;
    int p = (idx / 3136) & 1;
    int s = idx % 3136;
    int t = b * 3136 + s;
    out[idx] = O2[t * 2 + p] * O2[(size_t)T_TOK * 2 + t * 2 + p];
}

// ---------------------------------------------------------------------------
extern "C" void kernel_launch(void* const* d_in, const int* in_sizes, int n_in,
                              void* d_out, int out_size, void* d_ws, size_t ws_size,
                              hipStream_t stream) {
    const float* x     = (const float*)d_in[0];
    const float* n1_g  = (const float*)d_in[1];
    const float* n1_b  = (const float*)d_in[2];
    const float* qkv_w = (const float*)d_in[3];
    const float* qkv_b = (const float*)d_in[4];
    const float* proj_w= (const float*)d_in[5];
    const float* proj_b= (const float*)d_in[6];
    const float* rpb   = (const float*)d_in[7];
    const float* n2_g  = (const float*)d_in[8];
    const float* n2_b  = (const float*)d_in[9];
    const float* fc1_w = (const float*)d_in[10];
    const float* fc1_b = (const float*)d_in[11];
    const float* fc2_w = (const float*)d_in[12];
    const float* fc2_b = (const float*)d_in[13];
    const float* hln_g = (const float*)d_in[14];
    const float* hln_b = (const float*)d_in[15];
    const float* c1_w  = (const float*)d_in[16];
    const float* c1_b  = (const float*)d_in[17];
    const float* c2_w  = (const float*)d_in[18];
    const float* c2_b  = (const float*)d_in[19];
    const int*   rpi   = (const int*)d_in[20];

    // ws: X f32 | BIG f32 (QKV bf16 pack; bf16 mlp-hidden overlay) |
    //     Y64 (rpbT overlay) | O2 | XWb bf16 | WB bf16 (WB1/WB2 = Bias2 overlay)
    float* ws   = (float*)d_ws;
    float* X    = ws;                                  // 4,816,896 f32
    float* BIG  = X + (size_t)T_TOK * CDIM;            // 14,450,688 f32
    float* Y64  = BIG + (size_t)T_TOK * 2304;          // 401,408 f32
    float* O2   = Y64 + (size_t)T_TOK * 64;            // 25,088 f32
    ushort_t* XWb = (ushort_t*)(O2 + 2 * T_TOK * 2);
    ushort_t* WB  = XWb + (size_t)T_TOK * CDIM;
    ushort_t* WBq = WB;
    ushort_t* WBp = WBq + (size_t)2304 * 768;
    ushort_t* WB1 = WBp + (size_t)768 * 768;
    ushort_t* WB2 = WB1 + (size_t)3072 * 768;
    ushort_t* BIGb = (ushort_t*)BIG;                   // bf16 mlp hidden overlay
    ushort_t* QKVb = (ushort_t*)BIG;                   // bf16 QKV pack overlay
    ushort_t* BiasT = WB1;                             // Bias2 overlay: 7.99MB <= 9.44MB
    float* rpbT = Y64;                                 // 60,840 f32 overlay (Y64 free until head)

    const int NQ = 2304 * 768, NP = 768 * 768, N1 = 3072 * 768, N2 = 768 * 3072;

    for (int br = 0; br < 2; ++br) {
        k_transpose_in<<<dim3(98, 24, 2), dim3(32, 8), 0, stream>>>(x, X);
        for (int bl = 0; bl < 2; ++bl) {
            int pb = br * 2 + bl;
            int shifted = bl;
            // weight conversion f32 -> bf16 (qkv/proj now; fc1/fc2 after attention,
            // since their region holds the bias table during attention)
            k_f2b<<<(NQ / 4 + 255) / 256, 256, 0, stream>>>(qkv_w + (size_t)pb * NQ, WBq, NQ / 4);
            k_f2b<<<(NP / 4 + 255) / 256, 256, 0, stream>>>(proj_w + (size_t)pb * NP, WBp, NP / 4);

            // bias table precompute: rpbT then Bias2[24][25][26][256]
            k_rpbT<<<(24 * 2535 + 255) / 256, 256, 0, stream>>>(rpb + (size_t)pb * 2535 * 24, rpbT);
            k_bias<<<24 * 25, 256, 0, stream>>>(rpbT, rpi, BiasT);

            k_ln_bf<<<T_TOK, 256, 0, stream>>>(X, XWb, n1_g + pb * 768, n1_b + pb * 768, shifted ? 2 : 1);
            // QKV GEMM -> bf16 pack (Q pre-scaled by QSCALE)
            k_gemm_mfma<<<dim3(18, 49), 256, 0, stream>>>(XWb, WBq, qkv_b + pb * 2304,
                                                          (float*)0, QKVb,
                                                          T_TOK, 2304, 768, 0, 0, 0, 2);
            k_attn_mfma<<<NWIN * NHEADS * 2, 256, 0, stream>>>(QKVb, BiasT, XWb, shifted);

            // fc weights now (bias table dead)
            k_f2b<<<(N1 / 4 + 255) / 256, 256, 0, stream>>>(fc1_w + (size_t)pb * N1, WB1, N1 / 4);
            k_f2b<<<(N2 / 4 + 255) / 256, 256, 0, stream>>>(fc2_w + (size_t)pb * N2, WB2, N2 / 4);

            k_gemm_mfma<<<dim3(6, 49), 256, 0, stream>>>(XWb, WBp, proj_b + pb * 768,
                                                         X, (ushort_t*)0,
                                                         T_TOK, 768, 768, 0, shifted ? 2 : 1, 1, 0);
            k_ln_bf<<<T_TOK, 256, 0, stream>>>(X, XWb, n2_g + pb * 768, n2_b + pb * 768, 0);
            k_gemm_mfma<<<dim3(24, 49), 256, 0, stream>>>(XWb, WB1, fc1_b + pb * 3072,
                                                          (float*)0, BIGb,
                                                          T_TOK, 3072, 768, 1, 0, 0, 1);
            k_gemm_mfma<<<dim3(6, 49), 256, 0, stream>>>(BIGb, WB2, fc2_b + pb * 768,
                                                         X, (ushort_t*)0,
                                                         T_TOK, 768, 3072, 0, 0, 1, 0);
        }
        // head: all f32 (BIG free here, reuse for LN output)
        k_ln_f32<<<T_TOK, 256, 0, stream>>>(X, BIG, hln_g + br * 768, hln_b + br * 768);
        k_gemm_f32<<<dim3(1, 98), 256, 0, stream>>>(BIG, c1_w + (size_t)br * 64 * 768,
                                                    c1_b + br * 64, Y64,
                                                    T_TOK, 64, 768, 1);
        k_head_c2<<<(T_TOK * 2 + 255) / 256, 256, 0, stream>>>(Y64, c2_w + br * 128, c2_b + br * 2,
                                                               O2 + (size_t)br * T_TOK * 2);
    }
    k_final<<<(2 * 2 * 3136 + 255) / 256, 256, 0, stream>>>(O2, (float*)d_out);
}